// Round 7
// baseline (81.981 us; speedup 1.0000x reference)
//
#include <hip/hip_runtime.h>

#define DIM 256
#define L_ 128
#define TD 64
#define NVOCAB 150
#define NB 2048

__device__ __forceinline__ float dot4(float4 a, float4 b) {
    return fmaf(a.x, b.x, fmaf(a.y, b.y, fmaf(a.z, b.z, a.w * b.w)));
}

// ---------------------------------------------------------------------------
// Kernel A: M[c][d] = (1/16) * sum_e Wq[e][c] * Wk[e][d]   (256x256)
//           plus per-vocab scalar tables (BETA=0.5 folded in):
//           rel_s[v] = 0.5 * dot(rel_emb_w[v], Wrp[0:64])
//           pos_s[v] = 0.5 * dot(pos_emb_w[v], Wrp[64:128])
// ---------------------------------------------------------------------------
__global__ __launch_bounds__(256) void prep_kernel(
    const float* __restrict__ Wk, const float* __restrict__ Wq,
    const float* __restrict__ Wrp,
    const float* __restrict__ rel_emb_w, const float* __restrict__ pos_emb_w,
    float* __restrict__ M, float* __restrict__ rel_s, float* __restrict__ pos_s)
{
    if (blockIdx.x == DIM) {
        int v = threadIdx.x;
        if (v < NVOCAB) {
            float sr = 0.f, sp = 0.f;
#pragma unroll 8
            for (int j = 0; j < TD; ++j) {
                sr = fmaf(rel_emb_w[v * TD + j], Wrp[j], sr);
                sp = fmaf(pos_emb_w[v * TD + j], Wrp[TD + j], sp);
            }
            rel_s[v] = 0.5f * sr;
            pos_s[v] = 0.5f * sp;
        }
        return;
    }
    int cc = blockIdx.x;   // uniform per block -> Wq reads are scalar loads
    int d  = threadIdx.x;
    float a0 = 0.f, a1 = 0.f, a2 = 0.f, a3 = 0.f;
#pragma unroll 8
    for (int e = 0; e < DIM; e += 4) {
        a0 = fmaf(Wq[(e + 0) * DIM + cc], Wk[(e + 0) * DIM + d], a0);
        a1 = fmaf(Wq[(e + 1) * DIM + cc], Wk[(e + 1) * DIM + d], a1);
        a2 = fmaf(Wq[(e + 2) * DIM + cc], Wk[(e + 2) * DIM + d], a2);
        a3 = fmaf(Wq[(e + 3) * DIM + cc], Wk[(e + 3) * DIM + d], a3);
    }
    M[cc * DIM + d] = (a0 + a1 + a2 + a3) * (1.0f / 16.0f);  // temp = 16
}

// ---------------------------------------------------------------------------
// Kernel B (fused): blocks [0,256): qk = hn @ M.
//                   blocks [256,1280): bias_g[b*L+l] = mask ? -1e30 : rel+pos
// ---------------------------------------------------------------------------
__global__ __launch_bounds__(256) void qk_bias_kernel(
    const float* __restrict__ hn, const float* __restrict__ M,
    const int* __restrict__ pos_ind, const int* __restrict__ rel_dt,
    const float* __restrict__ rel_s, const float* __restrict__ pos_s,
    float* __restrict__ qk, float* __restrict__ bias_g)
{
    const int t = threadIdx.x;
    if (blockIdx.x >= NB / 8) {
        int idx = (blockIdx.x - NB / 8) * 256 + t;   // [0, NB*L_) exactly
        int pi = pos_ind[idx];
        int rd = rel_dt[idx];
        bias_g[idx] = (pi == 0) ? -1e30f : (rel_s[rd] + pos_s[pi]);
        return;
    }
    __shared__ float hn_s[8][DIM];
    const int r0 = blockIdx.x * 8;
#pragma unroll
    for (int i = 0; i < 8; ++i)
        hn_s[i][t] = hn[(size_t)(r0 + i) * DIM + t];
    __syncthreads();
    float acc[8] = {0.f, 0.f, 0.f, 0.f, 0.f, 0.f, 0.f, 0.f};
#pragma unroll 8
    for (int c = 0; c < DIM; ++c) {
        float m = M[c * DIM + t];
#pragma unroll
        for (int r = 0; r < 8; ++r)
            acc[r] = fmaf(hn_s[r][c], m, acc[r]);
    }
#pragma unroll
    for (int r = 0; r < 8; ++r)
        qk[(size_t)(r0 + r) * DIM + t] = acc[r];
}

// ---------------------------------------------------------------------------
// Kernel C: ONE WAVE = ONE b. 512 blocks x 256 threads (4 waves) = 2048
// waves; whole grid resident (2 blocks/CU). Wave partitioned into 4 groups
// of 16 lanes; group g streams rows {rb+g}, rb = 0,4,...,124 (32 rows),
// double-buffered (va/vb). Lane c owns cols {64j+4c..4c+3}. Logit = 4-step
// shfl_xor allreduce over the group. NO-MAX softmax (|logit|<~6 unmasked;
// masked bias -1e30 -> exp()==0), so state is a pure sum; cross-group merge
// is 34 shfl_xor in-register. ZERO barriers, ZERO LDS: the load stream is
// never drained.
// ---------------------------------------------------------------------------
__global__ __launch_bounds__(256) void attn_wave(
    const float* __restrict__ outp, const float* __restrict__ qk,
    const float* __restrict__ bias_g, float* __restrict__ y)
{
    const int w    = threadIdx.x >> 6;
    const int lane = threadIdx.x & 63;
    const int g    = lane >> 4;
    const int c    = lane & 15;
    const int b    = (blockIdx.x << 2) | w;

    const float4* __restrict__ src = (const float4*)outp + (size_t)b * (L_ * 64);
    const float4* __restrict__ qp  = (const float4*)qk + (size_t)b * 64;
    const float*  __restrict__ bp  = bias_g + (size_t)b * L_;

    float4 q[4];
#pragma unroll
    for (int j = 0; j < 4; ++j) q[j] = qp[j * 16 + c];

    float4 o[4];
#pragma unroll
    for (int j = 0; j < 4; ++j) o[j] = make_float4(0.f, 0.f, 0.f, 0.f);
    float d = 0.f;

    float4 va[4], vb[4];
    float biA, biB;

#define LOADV(BUF, ROW)                                            \
    do {                                                           \
        _Pragma("unroll")                                          \
        for (int j = 0; j < 4; ++j)                                \
            BUF[j] = src[(ROW) * 64 + j * 16 + c];                 \
    } while (0)

#define PROC(BUF, BI)                                              \
    do {                                                           \
        float p = dot4(BUF[0], q[0]) + dot4(BUF[1], q[1]) +        \
                  dot4(BUF[2], q[2]) + dot4(BUF[3], q[3]);         \
        p += __shfl_xor(p, 1);                                     \
        p += __shfl_xor(p, 2);                                     \
        p += __shfl_xor(p, 4);                                     \
        p += __shfl_xor(p, 8);                                     \
        float we = __expf(p + (BI));                               \
        d += we;                                                   \
        _Pragma("unroll")                                          \
        for (int j = 0; j < 4; ++j) {                              \
            o[j].x = fmaf(we, BUF[j].x, o[j].x);                   \
            o[j].y = fmaf(we, BUF[j].y, o[j].y);                   \
            o[j].z = fmaf(we, BUF[j].z, o[j].z);                   \
            o[j].w = fmaf(we, BUF[j].w, o[j].w);                   \
        }                                                          \
    } while (0)

    // prologue: rows g and 4+g in flight
    LOADV(va, g);         biA = bp[g];
    LOADV(vb, 4 + g);     biB = bp[4 + g];

    // steady state: process 8 rows/iter, keep 5-10 loads in flight
    for (int rb = 0; rb < L_ - 8; rb += 8) {
        PROC(va, biA);
        LOADV(va, rb + 8 + g);   biA = bp[rb + 8 + g];
        PROC(vb, biB);
        LOADV(vb, rb + 12 + g);  biB = bp[rb + 12 + g];
    }
    // epilogue: last 8 rows
    PROC(va, biA);
    PROC(vb, biB);
#undef LOADV
#undef PROC

    // ---- cross-group merge, all in-register (xor 16, 32) ----
#pragma unroll
    for (int j = 0; j < 4; ++j) {
        o[j].x += __shfl_xor(o[j].x, 16); o[j].y += __shfl_xor(o[j].y, 16);
        o[j].z += __shfl_xor(o[j].z, 16); o[j].w += __shfl_xor(o[j].w, 16);
        o[j].x += __shfl_xor(o[j].x, 32); o[j].y += __shfl_xor(o[j].y, 32);
        o[j].z += __shfl_xor(o[j].z, 32); o[j].w += __shfl_xor(o[j].w, 32);
    }
    d += __shfl_xor(d, 16);
    d += __shfl_xor(d, 32);

    const float inv = 1.0f / d;
    if (lane < 16) {
        float4* __restrict__ yo = (float4*)(y + (size_t)b * DIM);
#pragma unroll
        for (int j = 0; j < 4; ++j)
            yo[j * 16 + c] = make_float4(o[j].x * inv, o[j].y * inv,
                                         o[j].z * inv, o[j].w * inv);
    }
}

// ---------------------------------------------------------------------------
extern "C" void kernel_launch(void* const* d_in, const int* in_sizes, int n_in,
                              void* d_out, int out_size, void* d_ws, size_t ws_size,
                              hipStream_t stream)
{
    const float* out_t     = (const float*)d_in[0];  // [B, L, DIM]
    const float* hn        = (const float*)d_in[1];  // [B, DIM]
    const int*   pos_ind   = (const int*)  d_in[2];  // [B, L]
    const int*   rel_dt    = (const int*)  d_in[3];  // [B, L]
    // d_in[4] = abs_dt (unused)
    const float* pos_emb_w = (const float*)d_in[5];  // [VOCAB, TD]
    const float* rel_emb_w = (const float*)d_in[6];  // [VOCAB, TD]
    const float* Wk        = (const float*)d_in[7];  // [DIM, DIM]
    const float* Wq        = (const float*)d_in[8];  // [DIM, DIM]
    const float* Wrp       = (const float*)d_in[9];  // [1, 2*TD]

    float* y = (float*)d_out;                        // [B, DIM] fp32

    // ws layout (floats): M[65536] | qk[NB*DIM] | rel_s[256] | pos_s[256] | bias_g[NB*L]
    float* M      = (float*)d_ws;
    float* qk     = M + DIM * DIM;
    float* rel_s  = qk + (size_t)NB * DIM;
    float* pos_s  = rel_s + 256;
    float* bias_g = pos_s + 256;

    prep_kernel<<<DIM + 1, 256, 0, stream>>>(Wk, Wq, Wrp, rel_emb_w, pos_emb_w,
                                             M, rel_s, pos_s);
    qk_bias_kernel<<<NB / 8 + (NB * L_) / 256, 256, 0, stream>>>(
        hn, M, pos_ind, rel_dt, rel_s, pos_s, qk, bias_g);
    attn_wave<<<NB / 4, 256, 0, stream>>>(out_t, qk, bias_g, y);
}

// Round 8
// 81.281 us; speedup vs baseline: 1.0086x; 1.0086x over previous
//
#include <hip/hip_runtime.h>

#define DIM 256
#define L_ 128
#define TD 64
#define NVOCAB 150
#define NB 2048

__device__ __forceinline__ float dot4(float4 a, float4 b) {
    return fmaf(a.x, b.x, fmaf(a.y, b.y, fmaf(a.z, b.z, a.w * b.w)));
}

// ---------------------------------------------------------------------------
// SINGLE fused kernel. 512 blocks x 256 threads (4 waves). Block i owns
// b0 = 4i .. 4i+3. In-block prelude (redundant across blocks, L2-bound):
//   S0: hn[4][256] -> LDS; vocab tables rel_s/pos_s -> LDS (BETA folded)
//   S1: aq[4][256] = hn @ Wq^T   (16 groups x 16 lanes, shfl-reduced dots)
//   S2: qk[4][256] = aq @ Wk /16 (thread-per-(b,col4), aq LDS-broadcast)
// Phase C: wave w streams b = b0+w: 32 rows/group double-buffered, 4-step
// shfl_xor logit allreduce, NO-MAX softmax (|logit|<~6 unmasked; masked
// bias -1e30 -> exp()==0), in-register merge, zero barriers in the stream.
// First stream loads are issued BEFORE the prelude to keep HBM busy.
// ---------------------------------------------------------------------------
__global__ __launch_bounds__(256) void fused_kernel(
    const float* __restrict__ outp, const float* __restrict__ hn,
    const int* __restrict__ pos_ind, const int* __restrict__ rel_dt,
    const float* __restrict__ pos_emb_w, const float* __restrict__ rel_emb_w,
    const float* __restrict__ Wk, const float* __restrict__ Wq,
    const float* __restrict__ Wrp, float* __restrict__ y)
{
    const int t  = threadIdx.x;
    const int b0 = blockIdx.x << 2;

    const int w    = t >> 6;        // wave 0..3
    const int lane = t & 63;
    const int g    = lane >> 4;     // 16-lane group within wave
    const int c    = lane & 15;
    const int b    = b0 + w;

    __shared__ float hn_s[4][DIM];
    __shared__ float aq_s[4][DIM];
    __shared__ float qk_s[4][DIM];
    __shared__ float rel_s[NVOCAB];
    __shared__ float pos_s[NVOCAB];

    const float4* __restrict__ src = (const float4*)outp + (size_t)b * (L_ * 64);
    const int*    __restrict__ pip = pos_ind + (size_t)b * L_;
    const int*    __restrict__ rdp = rel_dt  + (size_t)b * L_;

    // ---- early prefetch: first 8 stream rows + their bias indices ----
    float4 va[4], vb[4];
    int piA, rdA, piB, rdB;
#pragma unroll
    for (int j = 0; j < 4; ++j) va[j] = src[g * 64 + j * 16 + c];
#pragma unroll
    for (int j = 0; j < 4; ++j) vb[j] = src[(4 + g) * 64 + j * 16 + c];
    piA = pip[g];     rdA = rdp[g];
    piB = pip[4 + g]; rdB = rdp[4 + g];

    // ---- S0: hn -> LDS, vocab tables -> LDS ----
#pragma unroll
    for (int i = 0; i < 4; ++i)
        hn_s[i][t] = hn[(size_t)(b0 + i) * DIM + t];
    if (t < NVOCAB) {
        float sr = 0.f, sp = 0.f;
#pragma unroll 8
        for (int j = 0; j < TD; ++j) {
            sr = fmaf(rel_emb_w[t * TD + j], Wrp[j], sr);
            sp = fmaf(pos_emb_w[t * TD + j], Wrp[TD + j], sp);
        }
        rel_s[t] = 0.5f * sr;
        pos_s[t] = 0.5f * sp;
    }
    __syncthreads();

    // ---- S1: aq[b][e] = sum_d hn[b][d] * Wq[e][d] ----
    {
        const int G = t >> 4;                    // group 0..15, e-range 16G..
        const float4* __restrict__ hn4 = (const float4*)hn_s;   // [4][64]
        float4 hf[4][4];
#pragma unroll
        for (int bb = 0; bb < 4; ++bb)
#pragma unroll
            for (int j = 0; j < 4; ++j)
                hf[bb][j] = hn4[bb * 64 + j * 16 + c];
        const float4* __restrict__ Wq4 = (const float4*)Wq;     // [256][64]
        for (int k = 0; k < 16; ++k) {
            const int e = (G << 4) + k;
            float4 wq[4];
#pragma unroll
            for (int j = 0; j < 4; ++j)
                wq[j] = Wq4[e * 64 + j * 16 + c];
#pragma unroll
            for (int bb = 0; bb < 4; ++bb) {
                float p = dot4(wq[0], hf[bb][0]) + dot4(wq[1], hf[bb][1])
                        + dot4(wq[2], hf[bb][2]) + dot4(wq[3], hf[bb][3]);
                p += __shfl_xor(p, 1);
                p += __shfl_xor(p, 2);
                p += __shfl_xor(p, 4);
                p += __shfl_xor(p, 8);
                if (c == bb) aq_s[bb][e] = p * 0.0625f;  // fold 1/temp (=16)
            }
        }
    }
    __syncthreads();

    // ---- S2: qk[b][d] = sum_e aq[b][e] * Wk[e][d] ----
    {
        const int b2 = t >> 6, d4 = t & 63;
        const float4* __restrict__ Wk4 = (const float4*)Wk;     // [256][64]
        const float4* __restrict__ aq4 = (const float4*)aq_s[b2];
        float4 acc = make_float4(0.f, 0.f, 0.f, 0.f);
        for (int e4 = 0; e4 < 64; ++e4) {
            const float4 a4 = aq4[e4];           // wave-uniform broadcast
            const float4 wk0 = Wk4[(e4 * 4 + 0) * 64 + d4];
            const float4 wk1 = Wk4[(e4 * 4 + 1) * 64 + d4];
            const float4 wk2 = Wk4[(e4 * 4 + 2) * 64 + d4];
            const float4 wk3 = Wk4[(e4 * 4 + 3) * 64 + d4];
            acc.x = fmaf(a4.x, wk0.x, acc.x); acc.y = fmaf(a4.x, wk0.y, acc.y);
            acc.z = fmaf(a4.x, wk0.z, acc.z); acc.w = fmaf(a4.x, wk0.w, acc.w);
            acc.x = fmaf(a4.y, wk1.x, acc.x); acc.y = fmaf(a4.y, wk1.y, acc.y);
            acc.z = fmaf(a4.y, wk1.z, acc.z); acc.w = fmaf(a4.y, wk1.w, acc.w);
            acc.x = fmaf(a4.z, wk2.x, acc.x); acc.y = fmaf(a4.z, wk2.y, acc.y);
            acc.z = fmaf(a4.z, wk2.z, acc.z); acc.w = fmaf(a4.z, wk2.w, acc.w);
            acc.x = fmaf(a4.w, wk3.x, acc.x); acc.y = fmaf(a4.w, wk3.y, acc.y);
            acc.z = fmaf(a4.w, wk3.z, acc.z); acc.w = fmaf(a4.w, wk3.w, acc.w);
        }
        ((float4*)qk_s[b2])[d4] = acc;
    }
    __syncthreads();

    // ---- Phase C: wave w streams b = b0 + w (zero barriers) ----
    float4 q[4];
#pragma unroll
    for (int j = 0; j < 4; ++j) q[j] = ((const float4*)qk_s[w])[j * 16 + c];

    float4 o[4];
#pragma unroll
    for (int j = 0; j < 4; ++j) o[j] = make_float4(0.f, 0.f, 0.f, 0.f);
    float d = 0.f;

#define LOADV(BUF, ROW)                                           \
    do { _Pragma("unroll")                                        \
        for (int j = 0; j < 4; ++j)                               \
            BUF[j] = src[(ROW) * 64 + j * 16 + c];                \
    } while (0)

#define PROC(BUF, PI, RD)                                         \
    do {                                                          \
        float p = dot4(BUF[0], q[0]) + dot4(BUF[1], q[1]) +       \
                  dot4(BUF[2], q[2]) + dot4(BUF[3], q[3]);        \
        p += __shfl_xor(p, 1);                                    \
        p += __shfl_xor(p, 2);                                    \
        p += __shfl_xor(p, 4);                                    \
        p += __shfl_xor(p, 8);                                    \
        float bi = ((PI) == 0) ? -1e30f                           \
                 : rel_s[(RD)] + pos_s[(PI)];                     \
        float we = __expf(p + bi);                                \
        d += we;                                                  \
        _Pragma("unroll")                                         \
        for (int j = 0; j < 4; ++j) {                             \
            o[j].x = fmaf(we, BUF[j].x, o[j].x);                  \
            o[j].y = fmaf(we, BUF[j].y, o[j].y);                  \
            o[j].z = fmaf(we, BUF[j].z, o[j].z);                  \
            o[j].w = fmaf(we, BUF[j].w, o[j].w);                  \
        }                                                         \
    } while (0)

    // va/vb for rows g, 4+g already in flight from the early prefetch
    for (int rb = 0; rb < L_ - 8; rb += 8) {
        PROC(va, piA, rdA);
        LOADV(va, rb + 8 + g);
        piA = pip[rb + 8 + g];  rdA = rdp[rb + 8 + g];
        PROC(vb, piB, rdB);
        LOADV(vb, rb + 12 + g);
        piB = pip[rb + 12 + g]; rdB = rdp[rb + 12 + g];
    }
    PROC(va, piA, rdA);
    PROC(vb, piB, rdB);
#undef LOADV
#undef PROC

    // ---- in-register cross-group merge (xor 16, 32) ----
#pragma unroll
    for (int j = 0; j < 4; ++j) {
        o[j].x += __shfl_xor(o[j].x, 16); o[j].y += __shfl_xor(o[j].y, 16);
        o[j].z += __shfl_xor(o[j].z, 16); o[j].w += __shfl_xor(o[j].w, 16);
        o[j].x += __shfl_xor(o[j].x, 32); o[j].y += __shfl_xor(o[j].y, 32);
        o[j].z += __shfl_xor(o[j].z, 32); o[j].w += __shfl_xor(o[j].w, 32);
    }
    d += __shfl_xor(d, 16);
    d += __shfl_xor(d, 32);

    const float inv = 1.0f / d;
    if (lane < 16) {
        float4* __restrict__ yo = (float4*)(y + (size_t)b * DIM);
#pragma unroll
        for (int j = 0; j < 4; ++j)
            yo[j * 16 + c] = make_float4(o[j].x * inv, o[j].y * inv,
                                         o[j].z * inv, o[j].w * inv);
    }
}

// ---------------------------------------------------------------------------
extern "C" void kernel_launch(void* const* d_in, const int* in_sizes, int n_in,
                              void* d_out, int out_size, void* d_ws, size_t ws_size,
                              hipStream_t stream)
{
    const float* out_t     = (const float*)d_in[0];  // [B, L, DIM]
    const float* hn        = (const float*)d_in[1];  // [B, DIM]
    const int*   pos_ind   = (const int*)  d_in[2];  // [B, L]
    const int*   rel_dt    = (const int*)  d_in[3];  // [B, L]
    // d_in[4] = abs_dt (unused)
    const float* pos_emb_w = (const float*)d_in[5];  // [VOCAB, TD]
    const float* rel_emb_w = (const float*)d_in[6];  // [VOCAB, TD]
    const float* Wk        = (const float*)d_in[7];  // [DIM, DIM]
    const float* Wq        = (const float*)d_in[8];  // [DIM, DIM]
    const float* Wrp       = (const float*)d_in[9];  // [1, 2*TD]

    float* y = (float*)d_out;                        // [B, DIM] fp32

    fused_kernel<<<NB / 4, 256, 0, stream>>>(
        out_t, hn, pos_ind, rel_dt, pos_emb_w, rel_emb_w, Wk, Wq, Wrp, y);
}

// Round 10
// 71.181 us; speedup vs baseline: 1.1517x; 1.1419x over previous
//
#include <hip/hip_runtime.h>

#define DIM 256
#define L_ 128
#define TD 64
#define NVOCAB 150
#define NB 2048

typedef float floatx4 __attribute__((ext_vector_type(4)));

__device__ __forceinline__ float dot4(float4 a, float4 b) {
    return fmaf(a.x, b.x, fmaf(a.y, b.y, fmaf(a.z, b.z, a.w * b.w)));
}

__device__ __forceinline__ float4 nt_load4(const float4* p) {
    floatx4 r = __builtin_nontemporal_load((const floatx4*)p);
    return make_float4(r.x, r.y, r.z, r.w);
}

// ---------------------------------------------------------------------------
// Kernel A: M[c][d] = (1/16) * sum_e Wq[e][c] * Wk[e][d]   (256x256)
//           plus per-vocab scalar tables (BETA=0.5 folded in):
//           rel_s[v] = 0.5 * dot(rel_emb_w[v], Wrp[0:64])
//           pos_s[v] = 0.5 * dot(pos_emb_w[v], Wrp[64:128])
// ---------------------------------------------------------------------------
__global__ __launch_bounds__(256) void prep_kernel(
    const float* __restrict__ Wk, const float* __restrict__ Wq,
    const float* __restrict__ Wrp,
    const float* __restrict__ rel_emb_w, const float* __restrict__ pos_emb_w,
    float* __restrict__ M, float* __restrict__ rel_s, float* __restrict__ pos_s)
{
    if (blockIdx.x == DIM) {
        int v = threadIdx.x;
        if (v < NVOCAB) {
            float sr = 0.f, sp = 0.f;
#pragma unroll 8
            for (int j = 0; j < TD; ++j) {
                sr = fmaf(rel_emb_w[v * TD + j], Wrp[j], sr);
                sp = fmaf(pos_emb_w[v * TD + j], Wrp[TD + j], sp);
            }
            rel_s[v] = 0.5f * sr;
            pos_s[v] = 0.5f * sp;
        }
        return;
    }
    int cc = blockIdx.x;   // uniform per block -> Wq reads become scalar loads
    int d  = threadIdx.x;
    float acc = 0.f;
#pragma unroll 16
    for (int e = 0; e < DIM; ++e)
        acc = fmaf(Wq[e * DIM + cc], Wk[e * DIM + d], acc);
    M[cc * DIM + d] = acc * (1.0f / 16.0f);   // temperature = sqrt(256) = 16
}

// ---------------------------------------------------------------------------
// Kernel B (fused): blocks [0,256): qk = hn @ M.
//                   blocks [256,1280): bias_g[b*L+l] = mask ? -1e30 : rel+pos
// ---------------------------------------------------------------------------
__global__ __launch_bounds__(256) void qk_bias_kernel(
    const float* __restrict__ hn, const float* __restrict__ M,
    const int* __restrict__ pos_ind, const int* __restrict__ rel_dt,
    const float* __restrict__ rel_s, const float* __restrict__ pos_s,
    float* __restrict__ qk, float* __restrict__ bias_g)
{
    const int t = threadIdx.x;
    if (blockIdx.x >= NB / 8) {
        int idx = (blockIdx.x - NB / 8) * 256 + t;   // [0, NB*L_) exactly
        int pi = pos_ind[idx];
        int rd = rel_dt[idx];
        bias_g[idx] = (pi == 0) ? -1e30f : (rel_s[rd] + pos_s[pi]);
        return;
    }
    __shared__ float hn_s[8][DIM];
    const int r0 = blockIdx.x * 8;
#pragma unroll
    for (int i = 0; i < 8; ++i)
        hn_s[i][t] = hn[(size_t)(r0 + i) * DIM + t];
    __syncthreads();
    float acc[8] = {0.f, 0.f, 0.f, 0.f, 0.f, 0.f, 0.f, 0.f};
#pragma unroll 8
    for (int c = 0; c < DIM; ++c) {
        float m = M[c * DIM + t];
#pragma unroll
        for (int r = 0; r < 8; ++r)
            acc[r] = fmaf(hn_s[r][c], m, acc[r]);
    }
#pragma unroll
    for (int r = 0; r < 8; ++r)
        qk[(size_t)(r0 + r) * DIM + t] = acc[r];
}

// ---------------------------------------------------------------------------
// Kernel C (R3 structure + nt loads): one block per b, 512 threads = 8
// waves, 32 groups of 16 lanes. Group grp = 4w+g owns rows {r0+4k},
// r0 = 16w+g; lane c holds 16 cols. ALL 16 float4 loads issue up-front
// (burst: ~128 KB outstanding per block). Nontemporal: the 268 MB stream
// is read once and thrashes L3 anyway, so skip cache allocation.
// ---------------------------------------------------------------------------
__global__ __launch_bounds__(512, 4) void attn_main(
    const float* __restrict__ outp, const float* __restrict__ qk,
    const float* __restrict__ bias_g, float* __restrict__ y)
{
    const int b    = blockIdx.x;
    const int t    = threadIdx.x;
    const int w    = t >> 6;
    const int lane = t & 63;
    const int g    = lane >> 4;
    const int c    = lane & 15;
    const int grp  = (w << 2) | g;

    __shared__ float mG[32];
    __shared__ float dG[32];
    __shared__ float red[32][DIM];

    // float4 view of out[b]: (row, j, c) -> row*64 + j*16 + c
    const float4* __restrict__ src = (const float4*)outp + (size_t)b * (L_ * 64);
    const int r0   = (w << 4) | g;
    const int base = r0 * 64 + c;

    // ---- issue ALL data loads immediately (nontemporal burst) ----
    float4 v[16];
#pragma unroll
    for (int k = 0; k < 4; ++k)
#pragma unroll
        for (int j = 0; j < 4; ++j)
            v[k * 4 + j] = nt_load4(&src[base + k * 256 + j * 16]);

    // qk fragment (L2-hot) and this group's 4 row biases
    const float4* __restrict__ qp = (const float4*)qk + (size_t)b * 64;
    float4 q[4];
#pragma unroll
    for (int j = 0; j < 4; ++j) q[j] = qp[c + j * 16];
    const float* __restrict__ bp = bias_g + (size_t)b * L_ + r0;
    float bi[4];
#pragma unroll
    for (int k = 0; k < 4; ++k) bi[k] = bp[4 * k];

    // ---- 4 logits: partial dots + 16-lane allreduce (chains overlap) ----
    float lg[4];
#pragma unroll
    for (int k = 0; k < 4; ++k) {
        float p = dot4(v[k * 4 + 0], q[0]) + dot4(v[k * 4 + 1], q[1]) +
                  dot4(v[k * 4 + 2], q[2]) + dot4(v[k * 4 + 3], q[3]);
        p += __shfl_xor(p, 1);
        p += __shfl_xor(p, 2);
        p += __shfl_xor(p, 4);
        p += __shfl_xor(p, 8);
        lg[k] = p + bi[k];
    }

    // ---- group-local softmax ----
    const float m = fmaxf(fmaxf(lg[0], lg[1]), fmaxf(lg[2], lg[3]));
    float we[4];
    float d = 0.f;
#pragma unroll
    for (int k = 0; k < 4; ++k) { we[k] = __expf(lg[k] - m); d += we[k]; }

    // ---- single weighted accumulate ----
    float4 o[4];
#pragma unroll
    for (int j = 0; j < 4; ++j) o[j] = make_float4(0.f, 0.f, 0.f, 0.f);
#pragma unroll
    for (int k = 0; k < 4; ++k)
#pragma unroll
        for (int j = 0; j < 4; ++j) {
            o[j].x = fmaf(we[k], v[k * 4 + j].x, o[j].x);
            o[j].y = fmaf(we[k], v[k * 4 + j].y, o[j].y);
            o[j].z = fmaf(we[k], v[k * 4 + j].z, o[j].z);
            o[j].w = fmaf(we[k], v[k * 4 + j].w, o[j].w);
        }

    // ---- merge 32 group states ----
    if (c == 0) { mG[grp] = m; dG[grp] = d; }
    __syncthreads();

    float Mx = -1e30f;
#pragma unroll
    for (int i = 0; i < 32; ++i) Mx = fmaxf(Mx, mG[i]);   // LDS broadcasts
    float term = (lane < 32) ? __expf(mG[lane] - Mx) * dG[lane] : 0.f;
#pragma unroll
    for (int off = 32; off >= 1; off >>= 1) term += __shfl_xor(term, off, 64);
    const float f = __expf(m - Mx) / term;

    float4* rw = (float4*)(&red[grp][0]);
#pragma unroll
    for (int j = 0; j < 4; ++j)
        rw[c + j * 16] = make_float4(o[j].x * f, o[j].y * f, o[j].z * f, o[j].w * f);
    __syncthreads();

    if (t < DIM) {
        float s = 0.f;
#pragma unroll
        for (int gg = 0; gg < 32; ++gg) s += red[gg][t];   // 2-way banked, free
        y[(size_t)b * DIM + t] = s;
    }
}

// ---------------------------------------------------------------------------
extern "C" void kernel_launch(void* const* d_in, const int* in_sizes, int n_in,
                              void* d_out, int out_size, void* d_ws, size_t ws_size,
                              hipStream_t stream)
{
    const float* out_t     = (const float*)d_in[0];  // [B, L, DIM]
    const float* hn        = (const float*)d_in[1];  // [B, DIM]
    const int*   pos_ind   = (const int*)  d_in[2];  // [B, L]
    const int*   rel_dt    = (const int*)  d_in[3];  // [B, L]
    // d_in[4] = abs_dt (unused)
    const float* pos_emb_w = (const float*)d_in[5];  // [VOCAB, TD]
    const float* rel_emb_w = (const float*)d_in[6];  // [VOCAB, TD]
    const float* Wk        = (const float*)d_in[7];  // [DIM, DIM]
    const float* Wq        = (const float*)d_in[8];  // [DIM, DIM]
    const float* Wrp       = (const float*)d_in[9];  // [1, 2*TD]

    float* y = (float*)d_out;                        // [B, DIM] fp32

    // ws layout (floats): M[65536] | qk[NB*DIM] | rel_s[256] | pos_s[256] | bias_g[NB*L]
    float* M      = (float*)d_ws;
    float* qk     = M + DIM * DIM;
    float* rel_s  = qk + (size_t)NB * DIM;
    float* pos_s  = rel_s + 256;
    float* bias_g = pos_s + 256;

    prep_kernel<<<DIM + 1, 256, 0, stream>>>(Wk, Wq, Wrp, rel_emb_w, pos_emb_w,
                                             M, rel_s, pos_s);
    qk_bias_kernel<<<NB / 8 + (NB * L_) / 256, 256, 0, stream>>>(
        hn, M, pos_ind, rel_dt, rel_s, pos_s, qk, bias_g);
    attn_main<<<NB, 512, 0, stream>>>(out_t, qk, bias_g, y);
}